// Round 1
// baseline (715.572 us; speedup 1.0000x reference)
//
#include <hip/hip_runtime.h>
#include <hip/hip_bf16.h>

// SparseMSDeformableAttention on MI355X — round 1: correctness-first full pipeline.
// Pipeline: vproj GEMM -> off GEMM -> attn GEMM -> bilinear sample/accumulate -> out GEMM.
// Dtype of inputs/outputs is ambiguous (reference says f32, harness threshold says bf16);
// we detect on-device and run the matching template instantiation (other twin early-exits).

#define LQ   13294
#define NTOK 26588   // 2 * 13294
#define DIM  256

// ---------- dtype helpers ----------
__device__ __forceinline__ float cvt(float x) { return x; }
__device__ __forceinline__ float cvt(__hip_bfloat16 x) { return __bfloat162float(x); }
__device__ __forceinline__ void stor(float* p, float v) { *p = v; }
__device__ __forceinline__ void stor(__hip_bfloat16* p, float v) { *p = __float2bfloat16(v); }

// ---------- dtype detection ----------
// If storage is bf16, even-indexed 16-bit halves are real bf16 values of N(0,1) data
// (sane exponents). If storage is f32, even-indexed halves are the LOW mantissa bits of
// f32 values -> near-uniform random exponent when viewed as bf16 -> mostly insane.
__global__ void detect_dtype_k(const unsigned short* __restrict__ q, int* __restrict__ flag) {
    int i = threadIdx.x;  // 0..63
    int sane = 0;
    #pragma unroll
    for (int r = 0; r < 2; r++) {
        unsigned int w = ((unsigned int)q[2 * (i + 64 * r)]) << 16;
        float f = __uint_as_float(w);
        float af = fabsf(f);
        if (f == 0.f || (af >= 0.0009765625f && af <= 1024.f)) sane++;
    }
    int cnt = sane;
    #pragma unroll
    for (int d = 32; d; d >>= 1) cnt += __shfl_down(cnt, d, 64);
    if (i == 0) *flag = (cnt >= 96) ? 1 : 0;   // 1 = bf16 storage, 0 = f32 storage
}

// ---------- tiled GEMM: C[M][N] = A[M][256] @ W[N][256]^T + bias (+ zeta per-channel) ----------
// 64x64 tile, K-tile 32, 256 threads, 4x4 accum per thread, fp32 accumulate.
template <typename AT, typename WT, typename OT>
__global__ __launch_bounds__(256) void gemm_nt_k(
    const int* __restrict__ flag, int want_bf,
    const AT* __restrict__ A, const WT* __restrict__ W,
    const WT* __restrict__ bias, const WT* __restrict__ zeta,
    OT* __restrict__ C, int M, int N)
{
    if (*flag != want_bf) return;
    __shared__ float qs[64][33];
    __shared__ float ws_[64][33];
    const int tid = threadIdx.x;
    const int tx = tid & 15, ty = tid >> 4;
    const int m0 = blockIdx.x * 64;
    const int n0 = blockIdx.y * 64;
    const int lr = tid >> 3;         // 0..31
    const int lk = (tid & 7) * 4;    // 0,4,...,28
    float acc[4][4] = {};

    for (int k0 = 0; k0 < DIM; k0 += 32) {
        #pragma unroll
        for (int rr = 0; rr < 64; rr += 32) {
            int m = m0 + lr + rr;
            #pragma unroll
            for (int i = 0; i < 4; i++)
                qs[lr + rr][lk + i] = (m < M) ? cvt(A[(long)m * DIM + k0 + lk + i]) : 0.f;
            int n = n0 + lr + rr;    // always < N (N multiple of 64)
            #pragma unroll
            for (int i = 0; i < 4; i++)
                ws_[lr + rr][lk + i] = cvt(W[(long)n * DIM + k0 + lk + i]);
        }
        __syncthreads();
        #pragma unroll
        for (int kk = 0; kk < 32; kk++) {
            float a[4], b[4];
            #pragma unroll
            for (int i = 0; i < 4; i++) a[i] = qs[ty * 4 + i][kk];
            #pragma unroll
            for (int j = 0; j < 4; j++) b[j] = ws_[tx * 4 + j][kk];
            #pragma unroll
            for (int i = 0; i < 4; i++)
                #pragma unroll
                for (int j = 0; j < 4; j++)
                    acc[i][j] = fmaf(a[i], b[j], acc[i][j]);
        }
        __syncthreads();
    }

    #pragma unroll
    for (int i = 0; i < 4; i++) {
        int m = m0 + ty * 4 + i;
        if (m >= M) continue;
        #pragma unroll
        for (int j = 0; j < 4; j++) {
            int n = n0 + tx * 4 + j;
            float v = acc[i][j] + cvt(bias[n]);
            if (zeta) v *= cvt(zeta[n & 31]);   // zeta broadcast over head-channel
            stor(&C[(long)m * N + n], v);
        }
    }
}

// ---------- sampling: bilinear gather + softmax-weighted accumulate ----------
// One block per token (512 threads = 8 waves = 8 heads).
// Within a wave: half = point parity, c = lane&31 = head channel.
template <typename T>
__global__ __launch_bounds__(512) void msda_sample_k(
    const int* __restrict__ flag, int want_bf,
    const T* __restrict__ refp,          // [B][LQ][4][2]
    const float* __restrict__ v,         // [NTOK][256] (b-major)
    const float* __restrict__ off,       // [NTOK][256]
    const float* __restrict__ attn,      // [NTOK][128]
    float* __restrict__ outp)            // [NTOK][256]
{
    if (*flag != want_bf) return;
    const int t = blockIdx.x;            // 0..NTOK-1
    const int b = t / LQ;
    const int h = threadIdx.x >> 6;      // head = wave id
    const int lane = threadIdx.x & 63;
    const int half = lane >> 5;
    const int c = lane & 31;

    const float* offT = off + (long)t * 256 + h * 32;
    const float* attT = attn + (long)t * 128 + h * 16;
    const T* refT = refp + (long)t * 8;

    // softmax over 16 logits (broadcast loads; redundant per-lane, cheap)
    float mx = -1e30f;
    #pragma unroll
    for (int i = 0; i < 16; i++) mx = fmaxf(mx, attT[i]);
    float s = 0.f;
    #pragma unroll
    for (int i = 0; i < 16; i++) s += __expf(attT[i] - mx);
    const float inv_s = 1.f / s;

    const float* vb = v + (long)b * LQ * 256 + h * 32 + c;
    float accv = 0.f;

    #pragma unroll
    for (int pp = 0; pp < 8; pp++) {
        const int lvl = pp >> 1;                       // compile-time after unroll
        const int Wl = (lvl == 0) ? 100 : (lvl == 1) ? 50 : (lvl == 2) ? 25 : 13;
        const int Hl = Wl;
        const int st = (lvl == 0) ? 0 : (lvl == 1) ? 10000 : (lvl == 2) ? 12500 : 13125;
        const int pi = pp * 2 + half;                  // 0..15 across the two halves

        float ox = offT[pi * 2 + 0], oy = offT[pi * 2 + 1];
        float rx = cvt(refT[lvl * 2 + 0]), ry = cvt(refT[lvl * 2 + 1]);
        // x = ((2*loc-1)+1)*0.5*W - 0.5 = loc*W - 0.5 ; loc = ref + off/W
        float x = rx * (float)Wl + ox - 0.5f;
        float y = ry * (float)Hl + oy - 0.5f;
        float x0f = floorf(x), y0f = floorf(y);
        float wx = x - x0f, wy = y - y0f;
        int x0 = (int)x0f, y0 = (int)y0f;
        float a = __expf(attT[pi] - mx) * inv_s;

        const float* base = vb + (long)st * 256;
        bool x0i = (x0 >= 0) & (x0 < Wl);
        bool x1i = (x0 + 1 >= 0) & (x0 + 1 < Wl);
        bool y0i = (y0 >= 0) & (y0 < Hl);
        bool y1i = (y0 + 1 >= 0) & (y0 + 1 < Hl);
        float v00 = 0.f, v01 = 0.f, v10 = 0.f, v11 = 0.f;
        if (y0i & x0i) v00 = base[((long)y0 * Wl + x0) * 256];
        if (y0i & x1i) v01 = base[((long)y0 * Wl + x0 + 1) * 256];
        if (y1i & x0i) v10 = base[(((long)y0 + 1) * Wl + x0) * 256];
        if (y1i & x1i) v11 = base[(((long)y0 + 1) * Wl + x0 + 1) * 256];

        accv += a * (v00 * (1.f - wx) * (1.f - wy) + v01 * wx * (1.f - wy)
                   + v10 * (1.f - wx) * wy         + v11 * wx * wy);
    }

    accv += __shfl_down(accv, 32, 64);
    if (lane < 32) outp[(long)t * 256 + h * 32 + c] = accv;
}

extern "C" void kernel_launch(void* const* d_in, const int* in_sizes, int n_in,
                              void* d_out, int out_size, void* d_ws, size_t ws_size,
                              hipStream_t stream)
{
    // input order: 0 query, 1 reference_points, 2 value, 3 spatial_shapes(int32),
    // 4 W_value, 5 b_value, 6 W_off, 7 b_off, 8 W_attn, 9 b_attn, 10 W_out, 11 b_out, 12 zeta
    float* vproj  = (float*)d_ws;                         // NTOK*256
    float* offb   = vproj  + (long)NTOK * 256;            // NTOK*256
    float* attnb  = offb   + (long)NTOK * 256;            // NTOK*128
    float* outpre = attnb  + (long)NTOK * 128;            // NTOK*256
    int*   flag   = (int*)(outpre + (long)NTOK * 256);

    detect_dtype_k<<<1, 64, 0, stream>>>((const unsigned short*)d_in[0], flag);

    using bf = __hip_bfloat16;
    dim3 blk(256);
    dim3 g4((NTOK + 63) / 64, 4);   // N = 256
    dim3 g2((NTOK + 63) / 64, 2);   // N = 128

    // ---- value projection (+zeta) ----
    gemm_nt_k<bf, bf, float><<<g4, blk, 0, stream>>>(flag, 1,
        (const bf*)d_in[2], (const bf*)d_in[4], (const bf*)d_in[5], (const bf*)d_in[12],
        vproj, NTOK, 256);
    gemm_nt_k<float, float, float><<<g4, blk, 0, stream>>>(flag, 0,
        (const float*)d_in[2], (const float*)d_in[4], (const float*)d_in[5], (const float*)d_in[12],
        vproj, NTOK, 256);

    // ---- sampling offsets ----
    gemm_nt_k<bf, bf, float><<<g4, blk, 0, stream>>>(flag, 1,
        (const bf*)d_in[0], (const bf*)d_in[6], (const bf*)d_in[7], (const bf*)nullptr,
        offb, NTOK, 256);
    gemm_nt_k<float, float, float><<<g4, blk, 0, stream>>>(flag, 0,
        (const float*)d_in[0], (const float*)d_in[6], (const float*)d_in[7], (const float*)nullptr,
        offb, NTOK, 256);

    // ---- attention logits ----
    gemm_nt_k<bf, bf, float><<<g2, blk, 0, stream>>>(flag, 1,
        (const bf*)d_in[0], (const bf*)d_in[8], (const bf*)d_in[9], (const bf*)nullptr,
        attnb, NTOK, 128);
    gemm_nt_k<float, float, float><<<g2, blk, 0, stream>>>(flag, 0,
        (const float*)d_in[0], (const float*)d_in[8], (const float*)d_in[9], (const float*)nullptr,
        attnb, NTOK, 128);

    // ---- bilinear sampling + weighted accumulate ----
    msda_sample_k<bf><<<NTOK, 512, 0, stream>>>(flag, 1,
        (const bf*)d_in[1], vproj, offb, attnb, outpre);
    msda_sample_k<float><<<NTOK, 512, 0, stream>>>(flag, 0,
        (const float*)d_in[1], vproj, offb, attnb, outpre);

    // ---- output projection ----
    gemm_nt_k<float, bf, bf><<<g4, blk, 0, stream>>>(flag, 1,
        outpre, (const bf*)d_in[10], (const bf*)d_in[11], (const bf*)nullptr,
        (bf*)d_out, NTOK, 256);
    gemm_nt_k<float, float, float><<<g4, blk, 0, stream>>>(flag, 0,
        outpre, (const float*)d_in[10], (const float*)d_in[11], (const float*)nullptr,
        (float*)d_out, NTOK, 256);
}

// Round 6
// 414.083 us; speedup vs baseline: 1.7281x; 1.7281x over previous
//
#include <hip/hip_runtime.h>
#include <hip/hip_bf16.h>

// SparseMSDeformableAttention MI355X — round 6.
// DTYPE RESOLUTION (round-5 post-mortem): ALL inputs and the output are FLOAT32.
// Round 1 passed via its f32 twin (the on-device detector chose flag=0); rounds 2-5
// NaN'd because reading f32 buffers as bf16 turns ~0.4% of mantissa halves into NaN
// bit patterns. Threshold 0.034375 is ABSOLUTE with |out| up to ~454 -> ~7.6e-5
// relative budget -> f32 everywhere (no bf16 intermediates; MFMA moot: no fp32 MFMA).
//
// Pipeline (all f32):
//   gemm(value,  W_value, +b, *zeta) -> vproj  [NTOK][256]
//   gemm(query,  W_off,   +b)        -> offb   [NTOK][256]
//   gemm(query,  W_attn,  +b)        -> attnb  [NTOK][128]  (logits)
//   sample(refp, vproj, offb, attnb) -> outpre [NTOK][256]
//   gemm(outpre, W_out,   +b)        -> d_out  [NTOK][256]

#define LQ    13294
#define NTOK  26588
#define CHUNK 3324        // ceil(NTOK/8) for XCD swizzle

typedef __attribute__((ext_vector_type(4))) float float4_t;

// ---------------- VALU GEMM: C[M][N] = A[M][256] @ W[N][256]^T + bias (opt *zeta) ----------------
// 256 threads, tile 128(M) x 128(N), K-tile 32. Thread (tx=tid&15, ty=tid>>4)
// computes rows ty*8..+7, cols tx*8..+7 (8x8 acc). LDS transposed [k][m], stride
// 132 floats (rows 16B-aligned; staging writes 2-way = free; frag reads 4-way).
// __launch_bounds__(256,2): 256-VGPR cap — (256,4)'s 128 cap caused spill thrash (r5).
__global__ __launch_bounds__(256, 2) void gemm_v_k(
    const float* __restrict__ A,     // [M][256]
    const float* __restrict__ W,     // [N][256]
    const float* __restrict__ bias,  // [N]
    const float* __restrict__ zeta,  // [32] or nullptr
    float* __restrict__ C,           // [M][N]
    int M, int N)
{
    __shared__ __align__(16) float As[32][132];
    __shared__ __align__(16) float Bs[32][132];
    const int tid = threadIdx.x;
    const int tx = tid & 15, ty = tid >> 4;
    const int m0 = blockIdx.x * 128;
    const int n0 = blockIdx.y * 128;
    const int row = tid >> 1;           // 0..127
    const int ks  = (tid & 1) * 16;     // 0 or 16

    float acc[8][8] = {};
    const int  mA  = m0 + row;
    const bool mok = (mA < M);
    const float* ap = A + (long)mA * 256 + ks;
    const float* wp = W + (long)(n0 + row) * 256 + ks;   // n always < N

    for (int k0 = 0; k0 < 256; k0 += 32) {
        // ---- stage 32-wide K slab, transposed ----
        float ta[16], tb[16];
        if (mok) {
            #pragma unroll
            for (int q = 0; q < 4; q++)
                *(float4_t*)(ta + q * 4) = *(const float4_t*)(ap + k0 + q * 4);
        } else {
            #pragma unroll
            for (int j = 0; j < 16; j++) ta[j] = 0.f;
        }
        #pragma unroll
        for (int q = 0; q < 4; q++)
            *(float4_t*)(tb + q * 4) = *(const float4_t*)(wp + k0 + q * 4);
        #pragma unroll
        for (int j = 0; j < 16; j++) {
            As[ks + j][row] = ta[j];
            Bs[ks + j][row] = tb[j];
        }
        __syncthreads();

        // ---- compute ----
        #pragma unroll 4
        for (int kk = 0; kk < 32; kk++) {
            float4_t a0 = *(const float4_t*)&As[kk][ty * 8];
            float4_t a1 = *(const float4_t*)&As[kk][ty * 8 + 4];
            float4_t b0 = *(const float4_t*)&Bs[kk][tx * 8];
            float4_t b1 = *(const float4_t*)&Bs[kk][tx * 8 + 4];
            float av[8], bv[8];
            #pragma unroll
            for (int i = 0; i < 4; i++) { av[i] = a0[i]; av[i + 4] = a1[i]; }
            #pragma unroll
            for (int j = 0; j < 4; j++) { bv[j] = b0[j]; bv[j + 4] = b1[j]; }
            #pragma unroll
            for (int i = 0; i < 8; i++)
                #pragma unroll
                for (int j = 0; j < 8; j++)
                    acc[i][j] = fmaf(av[i], bv[j], acc[i][j]);
        }
        __syncthreads();
    }

    // ---- epilogue ----
    float bz[8], zz[8];
    #pragma unroll
    for (int c = 0; c < 8; c++) {
        int n = n0 + tx * 8 + c;
        bz[c] = bias[n];
        zz[c] = zeta ? zeta[n & 31] : 1.f;
    }
    #pragma unroll
    for (int r = 0; r < 8; r++) {
        int m = m0 + ty * 8 + r;
        if (m >= M) continue;
        float4_t o0, o1;
        #pragma unroll
        for (int c = 0; c < 4; c++) {
            o0[c] = (acc[r][c] + bz[c]) * zz[c];
            o1[c] = (acc[r][c + 4] + bz[c + 4]) * zz[c + 4];
        }
        *(float4_t*)(C + (long)m * N + n0 + tx * 8) = o0;
        *(float4_t*)(C + (long)m * N + n0 + tx * 8 + 4) = o1;
    }
}

// ---------------- sampler (fast design, all-f32) ----------------
// 512 threads = 8 waves = 8 heads; one block per token (XCD-swizzled).
// Lane = s*8+g: s = point slot (0..7, x2 iters -> 16 points), g = 4-channel group
// (float4 = 16B gathers, 8 groups x 4 = 32 channels/head).
__global__ __launch_bounds__(512) void sample_k(
    const float* __restrict__ refp,    // [NTOK][4][2]
    const float* __restrict__ v,       // [NTOK][256] (b-major)
    const float* __restrict__ off,     // [NTOK][256]
    const float* __restrict__ logit,   // [NTOK][128]
    float* __restrict__ outp)          // [NTOK][256]
{
    const int bid = blockIdx.x;
    const int t = (bid & 7) * CHUNK + (bid >> 3);
    if (t >= NTOK) return;
    const int b = (t >= LQ) ? 1 : 0;
    const int h = threadIdx.x >> 6;
    const int ln = threadIdx.x & 63;
    const int g = ln & 7;
    const int s = ln >> 3;

    // coalesced setup loads (duplicated across lane groups)
    float offv = off[(long)t * 256 + h * 32 + (ln & 31)];
    float lg   = logit[(long)t * 128 + h * 16 + (ln & 15)];
    float rv   = refp[(long)t * 8 + (ln & 7)];

    // softmax over 16-lane groups (groups hold identical copies)
    float mx = lg;
    #pragma unroll
    for (int d = 1; d < 16; d <<= 1) mx = fmaxf(mx, __shfl_xor(mx, d, 64));
    float ex = __expf(lg - mx);
    float sm = ex;
    #pragma unroll
    for (int d = 1; d < 16; d <<= 1) sm += __shfl_xor(sm, d, 64);
    const float wgt = ex / sm;          // weight of point (ln&15)

    float4_t acc = {0.f, 0.f, 0.f, 0.f};
    const float* vb = v + ((long)b * LQ) * 256 + h * 32 + g * 4;

    #pragma unroll
    for (int it = 0; it < 2; it++) {
        const int pi  = it * 8 + s;          // point index 0..15
        const int lvl = pi >> 2;             // level 0..3
        const int Wi  = (lvl == 0) ? 100 : (lvl == 1) ? 50 : (lvl == 2) ? 25 : 13;
        const int st  = (lvl == 0) ? 0 : (lvl == 1) ? 10000 : (lvl == 2) ? 12500 : 13125;
        const float Wf = (float)Wi;

        float ox = __shfl(offv, pi * 2, 64);
        float oy = __shfl(offv, pi * 2 + 1, 64);
        float a  = __shfl(wgt, pi, 64);
        float rx = __shfl(rv, lvl * 2, 64);
        float ry = __shfl(rv, lvl * 2 + 1, 64);

        // x = loc*W - 0.5, loc = ref + off/W  ->  x = ref*W + off - 0.5
        float x = rx * Wf + ox - 0.5f;
        float y = ry * Wf + oy - 0.5f;
        float xf = floorf(x), yf = floorf(y);
        float wx = x - xf, wy = y - yf;
        int x0 = (int)xf, y0 = (int)yf;

        float w00 = (1.f - wx) * (1.f - wy) * a;
        float w01 = wx * (1.f - wy) * a;
        float w10 = (1.f - wx) * wy * a;
        float w11 = wx * wy * a;

        bool x0i = (unsigned)x0 < (unsigned)Wi;
        bool x1i = (unsigned)(x0 + 1) < (unsigned)Wi;
        bool y0i = (unsigned)y0 < (unsigned)Wi;
        bool y1i = (unsigned)(y0 + 1) < (unsigned)Wi;

        const float* base = vb + (long)st * 256;
        long i00 = ((long)y0 * Wi + x0) * 256;

        if (y0i & x0i) {
            float4_t u = *(const float4_t*)(base + i00);
            #pragma unroll
            for (int c = 0; c < 4; c++) acc[c] += w00 * u[c];
        }
        if (y0i & x1i) {
            float4_t u = *(const float4_t*)(base + i00 + 256);
            #pragma unroll
            for (int c = 0; c < 4; c++) acc[c] += w01 * u[c];
        }
        if (y1i & x0i) {
            float4_t u = *(const float4_t*)(base + i00 + (long)Wi * 256);
            #pragma unroll
            for (int c = 0; c < 4; c++) acc[c] += w10 * u[c];
        }
        if (y1i & x1i) {
            float4_t u = *(const float4_t*)(base + i00 + (long)Wi * 256 + 256);
            #pragma unroll
            for (int c = 0; c < 4; c++) acc[c] += w11 * u[c];
        }
    }

    // reduce over point slots (lanes sharing g are stride-8)
    #pragma unroll
    for (int d = 32; d >= 8; d >>= 1) {
        acc.x += __shfl_down(acc.x, d, 64);
        acc.y += __shfl_down(acc.y, d, 64);
        acc.z += __shfl_down(acc.z, d, 64);
        acc.w += __shfl_down(acc.w, d, 64);
    }
    if (s == 0)
        *(float4_t*)(outp + (long)t * 256 + h * 32 + g * 4) = acc;
}

extern "C" void kernel_launch(void* const* d_in, const int* in_sizes, int n_in,
                              void* d_out, int out_size, void* d_ws, size_t ws_size,
                              hipStream_t stream)
{
    // inputs: 0 query, 1 reference_points, 2 value, 3 spatial_shapes(int32),
    // 4 W_value, 5 b_value, 6 W_off, 7 b_off, 8 W_attn, 9 b_attn, 10 W_out, 11 b_out, 12 zeta
    float* vproj  = (float*)d_ws;                 // NTOK*256
    float* offb   = vproj  + (long)NTOK * 256;    // NTOK*256
    float* attnb  = offb   + (long)NTOK * 256;    // NTOK*128
    float* outpre = attnb  + (long)NTOK * 128;    // NTOK*256

    dim3 blk(256);
    dim3 g256(208, 2);   // ceil(26588/128) x (256/128)
    dim3 g128(208, 1);   // N = 128

    gemm_v_k<<<g256, blk, 0, stream>>>(
        (const float*)d_in[2], (const float*)d_in[4],
        (const float*)d_in[5], (const float*)d_in[12],
        vproj, NTOK, 256);

    gemm_v_k<<<g256, blk, 0, stream>>>(
        (const float*)d_in[0], (const float*)d_in[6],
        (const float*)d_in[7], nullptr,
        offb, NTOK, 256);

    gemm_v_k<<<g128, blk, 0, stream>>>(
        (const float*)d_in[0], (const float*)d_in[8],
        (const float*)d_in[9], nullptr,
        attnb, NTOK, 128);

    sample_k<<<8 * CHUNK, 512, 0, stream>>>(
        (const float*)d_in[1], vproj, offb, attnb, outpre);

    gemm_v_k<<<g256, blk, 0, stream>>>(
        outpre, (const float*)d_in[10],
        (const float*)d_in[11], nullptr,
        (float*)d_out, NTOK, 256);
}

// Round 7
// 295.692 us; speedup vs baseline: 2.4200x; 1.4004x over previous
//
#include <hip/hip_runtime.h>
#include <hip/hip_bf16.h>

// SparseMSDeformableAttention MI355X — round 7.
// All storage f32 (round-6 resolution). Hedged MFMA reintroduction:
//  - vproj/off/attn GEMMs: bf16 MFMA 16x16x32, f32->bf16 CONVERT in LDS staging
//    (rounds 2-4 NaNs were f32-reinterpreted-as-bf16 inputs, not MFMA itself),
//    f32 accumulate + f32 epilogue/outputs.
//  - out GEMM: f32 VALU (direct output contributor; keeps precision), now with
//    register-prefetch software pipeline + mov-free inner loop.
//  - sampler: branchless corner handling (clamped indices, masked weights).

#define LQ    13294
#define NTOK  26588
#define CHUNK 3324        // ceil(NTOK/8) for XCD swizzle

typedef unsigned short ushort_t;
typedef __attribute__((ext_vector_type(8))) short short8;
typedef __attribute__((ext_vector_type(4))) float float4_t;

__device__ __forceinline__ ushort_t f2b(float f) {
    unsigned int x = __float_as_uint(f);
    return (ushort_t)((x + 0x7fffu + ((x >> 16) & 1u)) >> 16);   // RNE
}

// ---------------- bf16 MFMA GEMM: C[M][N] = A[M][256] @ W[N][256]^T + bias (opt *zeta) ----------------
// 256 threads = 4 waves; tile 128(M) x 64(N), K-tile 32. f32 inputs converted to
// bf16 during LDS staging (once per element per tile); LDS row stride 40 ushorts.
// Fragment maps (m89/m91-verified): A[m=ln&15][k=(ln>>4)*8+j]; B-op holds
// W[n=ln&15][same k]; D col=ln&15 (n), row=(ln>>4)*4+r (m).
__global__ __launch_bounds__(256) void gemm_mfma_k(
    const float* __restrict__ A,     // [M][256]
    const float* __restrict__ W,     // [N][256]
    const float* __restrict__ bias,  // [N]
    const float* __restrict__ zeta,  // [32] or nullptr
    float* __restrict__ C,           // [M][N] f32
    int M, int N)
{
    __shared__ __align__(16) ushort_t As[128 * 40];
    __shared__ __align__(16) ushort_t Bs[64 * 40];
    const int tid = threadIdx.x;
    const int m0 = blockIdx.x * 128;
    const int n0 = blockIdx.y * 64;
    const int w  = tid >> 6;
    const int ln = tid & 63;
    const int sr = tid >> 2;            // staging row 0..63
    const int sc = (tid & 3) * 8;       // staging col {0,8,16,24}

    float4_t acc[2][4] = {};

    for (int k0 = 0; k0 < 256; k0 += 32) {
        // ---- stage A rows sr, sr+64 (f32 -> bf16) ----
        #pragma unroll
        for (int rr = 0; rr < 128; rr += 64) {
            int m = m0 + sr + rr;
            short8 pk = {};
            if (m < M) {
                float4_t f0 = *(const float4_t*)(A + (long)m * 256 + k0 + sc);
                float4_t f1 = *(const float4_t*)(A + (long)m * 256 + k0 + sc + 4);
                #pragma unroll
                for (int j = 0; j < 4; j++) {
                    pk[j]     = (short)f2b(f0[j]);
                    pk[j + 4] = (short)f2b(f1[j]);
                }
            }
            *(short8*)(As + (sr + rr) * 40 + sc) = pk;
        }
        // ---- stage B row sr (n always < N) ----
        {
            int n = n0 + sr;
            float4_t f0 = *(const float4_t*)(W + (long)n * 256 + k0 + sc);
            float4_t f1 = *(const float4_t*)(W + (long)n * 256 + k0 + sc + 4);
            short8 pk;
            #pragma unroll
            for (int j = 0; j < 4; j++) {
                pk[j]     = (short)f2b(f0[j]);
                pk[j + 4] = (short)f2b(f1[j]);
            }
            *(short8*)(Bs + sr * 40 + sc) = pk;
        }
        __syncthreads();

        const int krow = (ln >> 4) * 8;
        short8 af[2], bfr[4];
        #pragma unroll
        for (int i = 0; i < 2; i++)
            af[i] = *(const short8*)(As + (w * 32 + i * 16 + (ln & 15)) * 40 + krow);
        #pragma unroll
        for (int j = 0; j < 4; j++)
            bfr[j] = *(const short8*)(Bs + (j * 16 + (ln & 15)) * 40 + krow);
        #pragma unroll
        for (int i = 0; i < 2; i++)
            #pragma unroll
            for (int j = 0; j < 4; j++)
                acc[i][j] = __builtin_amdgcn_mfma_f32_16x16x32_bf16(af[i], bfr[j], acc[i][j], 0, 0, 0);
        __syncthreads();
    }

    const int col = ln & 15;
    const int rq  = (ln >> 4) * 4;
    #pragma unroll
    for (int j = 0; j < 4; j++) {
        int n = n0 + j * 16 + col;
        float bz = bias[n];
        float zz = zeta ? zeta[n & 31] : 1.f;
        #pragma unroll
        for (int i = 0; i < 2; i++) {
            #pragma unroll
            for (int r = 0; r < 4; r++) {
                int m = m0 + w * 32 + i * 16 + rq + r;
                if (m < M) C[(long)m * N + n] = (acc[i][j][r] + bz) * zz;
            }
        }
    }
}

// ---------------- f32 VALU GEMM (output projection) ----------------
// 256 threads, tile 128x128, K-tile 32, 8x8 acc/thread. Register prefetch of the
// next K-slab overlaps global latency with compute. LDS transposed [k][m].
__global__ __launch_bounds__(256, 2) void gemm_v_k(
    const float* __restrict__ A,     // [M][256]
    const float* __restrict__ W,     // [N][256]
    const float* __restrict__ bias,  // [N]
    float* __restrict__ C,           // [M][N]
    int M, int N)
{
    __shared__ __align__(16) float As[32][132];
    __shared__ __align__(16) float Bs[32][132];
    const int tid = threadIdx.x;
    const int tx = tid & 15, ty = tid >> 4;
    const int m0 = blockIdx.x * 128;
    const int n0 = blockIdx.y * 128;
    const int row = tid >> 1;           // 0..127
    const int ks  = (tid & 1) * 16;     // 0 or 16

    float acc[8][8] = {};
    const int  mA  = m0 + row;
    const bool mok = (mA < M);
    const float* ap = A + (long)mA * 256 + ks;
    const float* wp = W + (long)(n0 + row) * 256 + ks;

    float ta[16], tb[16];
    // preload K-tile 0
    if (mok) {
        #pragma unroll
        for (int q = 0; q < 4; q++)
            *(float4_t*)(ta + q * 4) = *(const float4_t*)(ap + q * 4);
    } else {
        #pragma unroll
        for (int j = 0; j < 16; j++) ta[j] = 0.f;
    }
    #pragma unroll
    for (int q = 0; q < 4; q++)
        *(float4_t*)(tb + q * 4) = *(const float4_t*)(wp + q * 4);

    for (int k0 = 0; k0 < 256; k0 += 32) {
        // ---- commit staged regs to LDS (transposed) ----
        #pragma unroll
        for (int j = 0; j < 16; j++) {
            As[ks + j][row] = ta[j];
            Bs[ks + j][row] = tb[j];
        }
        __syncthreads();

        // ---- prefetch next K-slab (latency hidden under compute) ----
        if (k0 < 224) {
            if (mok) {
                #pragma unroll
                for (int q = 0; q < 4; q++)
                    *(float4_t*)(ta + q * 4) = *(const float4_t*)(ap + k0 + 32 + q * 4);
            }
            #pragma unroll
            for (int q = 0; q < 4; q++)
                *(float4_t*)(tb + q * 4) = *(const float4_t*)(wp + k0 + 32 + q * 4);
        }

        // ---- compute (mov-free: FMA directly on vector elements) ----
        #pragma unroll 4
        for (int kk = 0; kk < 32; kk++) {
            float4_t a0 = *(const float4_t*)&As[kk][ty * 8];
            float4_t a1 = *(const float4_t*)&As[kk][ty * 8 + 4];
            float4_t b0 = *(const float4_t*)&Bs[kk][tx * 8];
            float4_t b1 = *(const float4_t*)&Bs[kk][tx * 8 + 4];
            #pragma unroll
            for (int i = 0; i < 4; i++)
                #pragma unroll
                for (int j = 0; j < 4; j++) {
                    acc[i][j]         = fmaf(a0[i], b0[j], acc[i][j]);
                    acc[i][j + 4]     = fmaf(a0[i], b1[j], acc[i][j + 4]);
                    acc[i + 4][j]     = fmaf(a1[i], b0[j], acc[i + 4][j]);
                    acc[i + 4][j + 4] = fmaf(a1[i], b1[j], acc[i + 4][j + 4]);
                }
        }
        __syncthreads();
    }

    float bz[8];
    #pragma unroll
    for (int c = 0; c < 8; c++) bz[c] = bias[n0 + tx * 8 + c];
    #pragma unroll
    for (int r = 0; r < 8; r++) {
        int m = m0 + ty * 8 + r;
        if (m >= M) continue;
        float4_t o0, o1;
        #pragma unroll
        for (int c = 0; c < 4; c++) {
            o0[c] = acc[r][c] + bz[c];
            o1[c] = acc[r][c + 4] + bz[c + 4];
        }
        *(float4_t*)(C + (long)m * N + n0 + tx * 8) = o0;
        *(float4_t*)(C + (long)m * N + n0 + tx * 8 + 4) = o1;
    }
}

// ---------------- sampler (branchless corners) ----------------
// 512 threads = 8 waves = 8 heads; one block per token (XCD-swizzled).
// Lane = s*8+g: s = point slot (0..7, x2 iters -> 16 points), g = 4-channel group.
__global__ __launch_bounds__(512) void sample_k(
    const float* __restrict__ refp,    // [NTOK][4][2]
    const float* __restrict__ v,       // [NTOK][256] (b-major)
    const float* __restrict__ off,     // [NTOK][256]
    const float* __restrict__ logit,   // [NTOK][128]
    float* __restrict__ outp)          // [NTOK][256]
{
    const int bid = blockIdx.x;
    const int t = (bid & 7) * CHUNK + (bid >> 3);
    if (t >= NTOK) return;
    const int b = (t >= LQ) ? 1 : 0;
    const int h = threadIdx.x >> 6;
    const int ln = threadIdx.x & 63;
    const int g = ln & 7;
    const int s = ln >> 3;

    float offv = off[(long)t * 256 + h * 32 + (ln & 31)];
    float lg   = logit[(long)t * 128 + h * 16 + (ln & 15)];
    float rv   = refp[(long)t * 8 + (ln & 7)];

    // softmax over the 16-point groups (4 identical copies across the wave)
    float mx = lg;
    #pragma unroll
    for (int d = 1; d < 16; d <<= 1) mx = fmaxf(mx, __shfl_xor(mx, d, 64));
    float ex = __expf(lg - mx);
    float sm = ex;
    #pragma unroll
    for (int d = 1; d < 16; d <<= 1) sm += __shfl_xor(sm, d, 64);
    const float wgt = ex / sm;

    float4_t acc = {0.f, 0.f, 0.f, 0.f};
    const float* vb = v + ((long)b * LQ) * 256 + h * 32 + g * 4;

    #pragma unroll
    for (int it = 0; it < 2; it++) {
        const int pi  = it * 8 + s;
        const int lvl = pi >> 2;
        const int Wi  = (lvl == 0) ? 100 : (lvl == 1) ? 50 : (lvl == 2) ? 25 : 13;
        const int st  = (lvl == 0) ? 0 : (lvl == 1) ? 10000 : (lvl == 2) ? 12500 : 13125;
        const float Wf = (float)Wi;

        float ox = __shfl(offv, pi * 2, 64);
        float oy = __shfl(offv, pi * 2 + 1, 64);
        float a  = __shfl(wgt, pi, 64);
        float rx = __shfl(rv, lvl * 2, 64);
        float ry = __shfl(rv, lvl * 2 + 1, 64);

        float x = rx * Wf + ox - 0.5f;
        float y = ry * Wf + oy - 0.5f;
        float xf = floorf(x), yf = floorf(y);
        float wx = x - xf, wy = y - yf;
        int x0 = (int)xf, y0 = (int)yf;

        // masked bilinear weights + clamped (always-valid) indices
        float mx0 = ((unsigned)x0       < (unsigned)Wi) ? (1.f - wx) : 0.f;
        float mx1 = ((unsigned)(x0 + 1) < (unsigned)Wi) ? wx         : 0.f;
        float my0 = ((unsigned)y0       < (unsigned)Wi) ? (1.f - wy) * a : 0.f;
        float my1 = ((unsigned)(y0 + 1) < (unsigned)Wi) ? wy * a         : 0.f;
        int x0c = min(max(x0, 0), Wi - 1);
        int x1c = min(max(x0 + 1, 0), Wi - 1);
        int y0c = min(max(y0, 0), Wi - 1);
        int y1c = min(max(y0 + 1, 0), Wi - 1);

        const float* base = vb + (long)st * 256;
        const float* r0 = base + (long)y0c * Wi * 256;
        const float* r1 = base + (long)y1c * Wi * 256;
        float4_t u00 = *(const float4_t*)(r0 + x0c * 256);
        float4_t u01 = *(const float4_t*)(r0 + x1c * 256);
        float4_t u10 = *(const float4_t*)(r1 + x0c * 256);
        float4_t u11 = *(const float4_t*)(r1 + x1c * 256);

        float w00 = mx0 * my0, w01 = mx1 * my0, w10 = mx0 * my1, w11 = mx1 * my1;
        #pragma unroll
        for (int c = 0; c < 4; c++)
            acc[c] += w00 * u00[c] + w01 * u01[c] + w10 * u10[c] + w11 * u11[c];
    }

    #pragma unroll
    for (int d = 32; d >= 8; d >>= 1) {
        acc.x += __shfl_down(acc.x, d, 64);
        acc.y += __shfl_down(acc.y, d, 64);
        acc.z += __shfl_down(acc.z, d, 64);
        acc.w += __shfl_down(acc.w, d, 64);
    }
    if (s == 0)
        *(float4_t*)(outp + (long)t * 256 + h * 32 + g * 4) = acc;
}

extern "C" void kernel_launch(void* const* d_in, const int* in_sizes, int n_in,
                              void* d_out, int out_size, void* d_ws, size_t ws_size,
                              hipStream_t stream)
{
    // inputs: 0 query, 1 reference_points, 2 value, 3 spatial_shapes(int32),
    // 4 W_value, 5 b_value, 6 W_off, 7 b_off, 8 W_attn, 9 b_attn, 10 W_out, 11 b_out, 12 zeta
    float* vproj  = (float*)d_ws;                 // NTOK*256
    float* offb   = vproj  + (long)NTOK * 256;    // NTOK*256
    float* attnb  = offb   + (long)NTOK * 256;    // NTOK*128
    float* outpre = attnb  + (long)NTOK * 128;    // NTOK*256

    dim3 blk(256);
    dim3 gm256(208, 4);   // MFMA: ceil(26588/128) x (256/64)
    dim3 gm128(208, 2);   // MFMA: N = 128
    dim3 gv256(208, 2);   // VALU: ceil(26588/128) x (256/128)

    gemm_mfma_k<<<gm256, blk, 0, stream>>>(
        (const float*)d_in[2], (const float*)d_in[4],
        (const float*)d_in[5], (const float*)d_in[12],
        vproj, NTOK, 256);

    gemm_mfma_k<<<gm256, blk, 0, stream>>>(
        (const float*)d_in[0], (const float*)d_in[6],
        (const float*)d_in[7], nullptr,
        offb, NTOK, 256);

    gemm_mfma_k<<<gm128, blk, 0, stream>>>(
        (const float*)d_in[0], (const float*)d_in[8],
        (const float*)d_in[9], nullptr,
        attnb, NTOK, 128);

    sample_k<<<8 * CHUNK, 512, 0, stream>>>(
        (const float*)d_in[1], vproj, offb, attnb, outpre);

    gemm_v_k<<<gv256, blk, 0, stream>>>(
        outpre, (const float*)d_in[10],
        (const float*)d_in[11],
        (float*)d_out, NTOK, 256);
}

// Round 8
// 265.675 us; speedup vs baseline: 2.6934x; 1.1130x over previous
//
#include <hip/hip_runtime.h>
#include <hip/hip_bf16.h>

// SparseMSDeformableAttention MI355X — round 8.
// r7 post-mortem: MFMA GEMMs were staging-VALU-bound (in-loop f32->bf16 convert),
// sampler was 8x-redundant on per-point VALU.
//  - cvt_k: one memory-bound pass converts query/value/all-W to bf16 (RNE) in ws.
//  - gemm_mfma_k: pure-bf16 staging (short8 copies), 128x64 tile, 16x16x32 MFMA.
//    Used for ALL FOUR gemms (out-proj A = bf16 outpre written by sampler).
//  - sample_k: two-phase. Phase 1 (128 thr): softmax + bilinear weights + clamped
//    byte offsets -> 4KB LDS. Phase 2 (512 thr): pure gather+FMA. bf16 out.
// Workspace overlays: v_bf->attnb, q_bf->outpre (sequential-stream safe). 82.3 MB.

#define LQ    13294
#define NTOK  26588
#define CHUNK 3324        // ceil(NTOK/8) for XCD swizzle
#define NE    6806528     // NTOK*256

typedef unsigned short ushort_t;
typedef __attribute__((ext_vector_type(8))) short short8;
typedef __attribute__((ext_vector_type(4))) float float4_t;

__device__ __forceinline__ ushort_t f2b(float f) {
    unsigned int x = __float_as_uint(f);
    return (ushort_t)((x + 0x7fffu + ((x >> 16) & 1u)) >> 16);   // RNE
}

// ---------------- bulk f32 -> bf16 convert ----------------
__device__ __forceinline__ void cvt_seg(const float* __restrict__ s,
                                        ushort_t* __restrict__ d,
                                        int n4, int gid, int stride) {
    const float4_t* s4 = (const float4_t*)s;
    for (int i = gid; i < n4; i += stride) {
        float4_t f = s4[i];
        ushort4 o;
        o.x = f2b(f.x); o.y = f2b(f.y); o.z = f2b(f.z); o.w = f2b(f.w);
        *(ushort4*)(d + (long)i * 4) = o;
    }
}

__global__ __launch_bounds__(256) void cvt_k(
    const float* q, const float* v, const float* Wv, const float* Wo,
    const float* Wa, const float* Wout,
    ushort_t* q_bf, ushort_t* v_bf, ushort_t* Wv_bf, ushort_t* Wo_bf,
    ushort_t* Wa_bf, ushort_t* Wout_bf)
{
    const int gid = blockIdx.x * 256 + threadIdx.x;
    const int stride = gridDim.x * 256;
    cvt_seg(q,    q_bf,    NE / 4,      gid, stride);
    cvt_seg(v,    v_bf,    NE / 4,      gid, stride);
    cvt_seg(Wv,   Wv_bf,   65536 / 4,   gid, stride);
    cvt_seg(Wo,   Wo_bf,   131072 / 4,  gid, stride);
    cvt_seg(Wa,   Wa_bf,   32768 / 4,   gid, stride);
    cvt_seg(Wout, Wout_bf, 65536 / 4,   gid, stride);
}

// ---------------- bf16 MFMA GEMM: C[M][N] = A[M][256] @ W[N][256]^T + bias (opt *zeta) ----------------
// 256 threads = 4 waves; tile 128(M) x 64(N), K-tile 32; LDS row stride 40 ushorts.
// Fragment maps: A[m=ln&15][k=(ln>>4)*8+j]; B-op = W[n=ln&15][same k];
// D col=ln&15 (n), row=(ln>>4)*4+r (m).  (r7-validated on HW.)
__global__ __launch_bounds__(256) void gemm_mfma_k(
    const ushort_t* __restrict__ A,     // [M][256] bf16
    const ushort_t* __restrict__ W,     // [N][256] bf16
    const float* __restrict__ bias,     // [N] f32
    const float* __restrict__ zeta,     // [32] f32 or nullptr
    float* __restrict__ C,              // [M][N] f32
    int M, int N)
{
    __shared__ __align__(16) ushort_t As[128 * 40];
    __shared__ __align__(16) ushort_t Bs[64 * 40];
    const int tid = threadIdx.x;
    const int m0 = blockIdx.x * 128;
    const int n0 = blockIdx.y * 64;
    const int w  = tid >> 6;
    const int ln = tid & 63;
    const int sr = tid >> 2;            // staging row 0..63
    const int sc = (tid & 3) * 8;       // staging col {0,8,16,24}

    float4_t acc[2][4] = {};

    for (int k0 = 0; k0 < 256; k0 += 32) {
        #pragma unroll
        for (int rr = 0; rr < 128; rr += 64) {
            int m = m0 + sr + rr;
            short8 pk = {};
            if (m < M) pk = *(const short8*)(A + (long)m * 256 + k0 + sc);
            *(short8*)(As + (sr + rr) * 40 + sc) = pk;
        }
        {
            int n = n0 + sr;            // always < N
            *(short8*)(Bs + sr * 40 + sc) = *(const short8*)(W + (long)n * 256 + k0 + sc);
        }
        __syncthreads();

        const int krow = (ln >> 4) * 8;
        short8 af[2], bfr[4];
        #pragma unroll
        for (int i = 0; i < 2; i++)
            af[i] = *(const short8*)(As + (w * 32 + i * 16 + (ln & 15)) * 40 + krow);
        #pragma unroll
        for (int j = 0; j < 4; j++)
            bfr[j] = *(const short8*)(Bs + (j * 16 + (ln & 15)) * 40 + krow);
        #pragma unroll
        for (int i = 0; i < 2; i++)
            #pragma unroll
            for (int j = 0; j < 4; j++)
                acc[i][j] = __builtin_amdgcn_mfma_f32_16x16x32_bf16(af[i], bfr[j], acc[i][j], 0, 0, 0);
        __syncthreads();
    }

    const int col = ln & 15;
    const int rq  = (ln >> 4) * 4;
    #pragma unroll
    for (int j = 0; j < 4; j++) {
        int n = n0 + j * 16 + col;
        float bz = bias[n];
        float zz = zeta ? zeta[n & 31] : 1.f;
        #pragma unroll
        for (int i = 0; i < 2; i++) {
            #pragma unroll
            for (int r = 0; r < 4; r++) {
                int m = m0 + w * 32 + i * 16 + rq + r;
                if (m < M) C[(long)m * N + n] = (acc[i][j][r] + bz) * zz;
            }
        }
    }
}

// ---------------- sampler: two-phase ----------------
// One block per token (XCD-swizzled), 512 threads = 8 waves.
// Phase 1: 128 threads = (head h = tid>>4, point pi = tid&15) -> softmax weight,
//   masked bilinear weights, clamped corner byte-offsets -> LDS.
// Phase 2: lane (h = tid>>6, g = ln&7 channel group, s = ln>>3 point slot):
//   2 iters x (2 LDS b128 param reads + 4 float4 gathers + 16 FMA).
__global__ __launch_bounds__(512) void sample_k(
    const float* __restrict__ refp,    // [NTOK][4][2]
    const float* __restrict__ v,       // [NTOK][256] f32 (b-major)
    const float* __restrict__ off,     // [NTOK][256]
    const float* __restrict__ logit,   // [NTOK][128]
    ushort_t* __restrict__ outp)       // [NTOK][256] bf16
{
    __shared__ int   p_ofs[128][4];
    __shared__ float p_w[128][4];
    const int bid = blockIdx.x;
    const int t = (bid & 7) * CHUNK + (bid >> 3);
    if (t >= NTOK) return;             // whole block exits (before barrier)
    const int b = (t >= LQ) ? 1 : 0;
    const int tid = threadIdx.x;

    if (tid < 128) {
        const int h = tid >> 4, pi = tid & 15;
        const int lvl = pi >> 2;
        const int Wi  = (lvl == 0) ? 100 : (lvl == 1) ? 50 : (lvl == 2) ? 25 : 13;
        const int st  = (lvl == 0) ? 0 : (lvl == 1) ? 10000 : (lvl == 2) ? 12500 : 13125;
        const float Wf = (float)Wi;

        float lg = logit[(long)t * 128 + h * 16 + pi];
        float smax = lg;
        #pragma unroll
        for (int d = 1; d < 16; d <<= 1) smax = fmaxf(smax, __shfl_xor(smax, d, 64));
        float ex = __expf(lg - smax);
        float sm = ex;
        #pragma unroll
        for (int d = 1; d < 16; d <<= 1) sm += __shfl_xor(sm, d, 64);
        const float a = ex / sm;

        float ox = off[(long)t * 256 + h * 32 + pi * 2];
        float oy = off[(long)t * 256 + h * 32 + pi * 2 + 1];
        float rx = refp[(long)t * 8 + lvl * 2];
        float ry = refp[(long)t * 8 + lvl * 2 + 1];

        float x = rx * Wf + ox - 0.5f;
        float y = ry * Wf + oy - 0.5f;
        float xf = floorf(x), yf = floorf(y);
        float wx = x - xf, wy = y - yf;
        int x0 = (int)xf, y0 = (int)yf;

        float mx0 = ((unsigned)x0       < (unsigned)Wi) ? (1.f - wx) : 0.f;
        float mx1 = ((unsigned)(x0 + 1) < (unsigned)Wi) ? wx         : 0.f;
        float my0 = ((unsigned)y0       < (unsigned)Wi) ? (1.f - wy) * a : 0.f;
        float my1 = ((unsigned)(y0 + 1) < (unsigned)Wi) ? wy * a         : 0.f;
        int x0c = min(max(x0, 0), Wi - 1);
        int x1c = min(max(x0 + 1, 0), Wi - 1);
        int y0c = min(max(y0, 0), Wi - 1);
        int y1c = min(max(y0 + 1, 0), Wi - 1);

        int r0 = st + y0c * Wi, r1 = st + y1c * Wi;
        p_ofs[tid][0] = (r0 + x0c) << 10;   // *256 elem *4 B
        p_ofs[tid][1] = (r0 + x1c) << 10;
        p_ofs[tid][2] = (r1 + x0c) << 10;
        p_ofs[tid][3] = (r1 + x1c) << 10;
        p_w[tid][0] = mx0 * my0;
        p_w[tid][1] = mx1 * my0;
        p_w[tid][2] = mx0 * my1;
        p_w[tid][3] = mx1 * my1;
    }
    __syncthreads();

    const int h = tid >> 6, ln = tid & 63, g = ln & 7, s = ln >> 3;
    const char* vb = (const char*)(v + ((long)b * LQ) * 256 + h * 32 + g * 4);
    float4_t acc = {0.f, 0.f, 0.f, 0.f};

    #pragma unroll
    for (int it = 0; it < 2; it++) {
        const int task = h * 16 + it * 8 + s;
        int4     o = *(const int4*)p_ofs[task];
        float4_t w = *(const float4_t*)p_w[task];
        float4_t u00 = *(const float4_t*)(vb + o.x);
        float4_t u01 = *(const float4_t*)(vb + o.y);
        float4_t u10 = *(const float4_t*)(vb + o.z);
        float4_t u11 = *(const float4_t*)(vb + o.w);
        #pragma unroll
        for (int c = 0; c < 4; c++)
            acc[c] += w.x * u00[c] + w.y * u01[c] + w.z * u10[c] + w.w * u11[c];
    }

    #pragma unroll
    for (int d = 32; d >= 8; d >>= 1) {
        acc.x += __shfl_down(acc.x, d, 64);
        acc.y += __shfl_down(acc.y, d, 64);
        acc.z += __shfl_down(acc.z, d, 64);
        acc.w += __shfl_down(acc.w, d, 64);
    }
    if (s == 0) {
        ushort4 o;
        o.x = f2b(acc.x); o.y = f2b(acc.y); o.z = f2b(acc.z); o.w = f2b(acc.w);
        *(ushort4*)(outp + (long)t * 256 + h * 32 + g * 4) = o;
    }
}

extern "C" void kernel_launch(void* const* d_in, const int* in_sizes, int n_in,
                              void* d_out, int out_size, void* d_ws, size_t ws_size,
                              hipStream_t stream)
{
    // inputs: 0 query, 1 reference_points, 2 value, 3 spatial_shapes(int32),
    // 4 W_value, 5 b_value, 6 W_off, 7 b_off, 8 W_attn, 9 b_attn, 10 W_out, 11 b_out, 12 zeta
    char* ws = (char*)d_ws;
    float*    vproj   = (float*)ws;                                  // NE f32
    float*    offb    = (float*)(ws + (long)NE * 4);                 // NE f32
    // u1: v_bf (bf16, NE) then attnb (f32, NE/2) — sequential-stream overlay
    ushort_t* v_bf    = (ushort_t*)(ws + (long)NE * 8);
    float*    attnb   = (float*)(ws + (long)NE * 8);
    // u2: q_bf (bf16, NE) then outpre (bf16, NE) — overlay
    ushort_t* q_bf    = (ushort_t*)(ws + (long)NE * 10);
    ushort_t* outpre  = q_bf;
    ushort_t* Wv_bf   = (ushort_t*)(ws + (long)NE * 12);
    ushort_t* Wo_bf   = Wv_bf + 65536;
    ushort_t* Wa_bf   = Wo_bf + 131072;
    ushort_t* Wout_bf = Wa_bf + 32768;

    dim3 blk(256);
    dim3 gm256(208, 4);   // ceil(26588/128) x (256/64)
    dim3 gm128(208, 2);   // N = 128

    cvt_k<<<1024, blk, 0, stream>>>(
        (const float*)d_in[0], (const float*)d_in[2], (const float*)d_in[4],
        (const float*)d_in[6], (const float*)d_in[8], (const float*)d_in[10],
        q_bf, v_bf, Wv_bf, Wo_bf, Wa_bf, Wout_bf);

    gemm_mfma_k<<<gm256, blk, 0, stream>>>(
        v_bf, Wv_bf, (const float*)d_in[5], (const float*)d_in[12],
        vproj, NTOK, 256);

    gemm_mfma_k<<<gm256, blk, 0, stream>>>(
        q_bf, Wo_bf, (const float*)d_in[7], nullptr,
        offb, NTOK, 256);

    gemm_mfma_k<<<gm128, blk, 0, stream>>>(
        q_bf, Wa_bf, (const float*)d_in[9], nullptr,
        attnb, NTOK, 128);          // overwrites v_bf region (dead after gemm1)

    sample_k<<<8 * CHUNK, 512, 0, stream>>>(
        (const float*)d_in[1], vproj, offb, attnb, outpre);  // outpre overlays q_bf (dead)

    gemm_mfma_k<<<gm256, blk, 0, stream>>>(
        outpre, Wout_bf, (const float*)d_in[11], nullptr,
        (float*)d_out, NTOK, 256);
}